// Round 13
// baseline (2860.137 us; speedup 1.0000x reference)
//
#include <hip/hip_runtime.h>

typedef unsigned short u16;
typedef short s8v __attribute__((ext_vector_type(8)));   // 8 x bf16 (as shorts)
typedef float f4v __attribute__((ext_vector_type(4)));
typedef float f32x4 __attribute__((ext_vector_type(4)));

#define B_ 256
#define T_ 64
#define I_ 512
#define H_ 1024
#define O_ 2
#define M_ (T_*B_)   // 16384 rows in the big GEMMs
#define NTILES 1024  // (M_/128)*(H_/128)
#define NPERS  768   // persistent blocks = 256 CU x 3 resident

#define SPK0_OFF ((size_t)0)
#define SPK1_OFF ((size_t)T_*B_*H_)                  // 16777216
#define SPK2_OFF ((size_t)2*T_*B_*H_)                // 33554432
#define MEM0_OFF ((size_t)2*T_*B_*H_ + (size_t)T_*B_*O_)
#define MEM1_OFF (MEM0_OFF + (size_t)T_*B_*H_)
#define MEM2_OFF (MEM1_OFF + (size_t)T_*B_*H_)

// ---- workspace layout (floats) ----
// [0]=flag, [8..9]=tile counters (fast path), fallback state at 1024+.
#define WS_CTR 8
#define WS_MEM0 1024
#define WS_MEM1 (1024 + B_*H_)
#define WS_MEM2 (1024 + 2*B_*H_)
#define WS_TOTAL (1024 + 2*B_*H_ + B_*O_)
#define WS_CUR2 1024
#define WS_CUR  (1024 + T_*B_*O_)
#define WS_FAST_TOTAL ((size_t)WS_CUR + (size_t)M_*H_)   // floats

typedef const __attribute__((address_space(1))) float glb_f;
typedef __attribute__((address_space(3))) float lds_f;

__device__ __forceinline__ float b2f(u16 u) {
    return __uint_as_float(((unsigned)u) << 16);
}
__device__ __forceinline__ u16 f2b(float f) {  // RNE
    unsigned u = __float_as_uint(f);
    return (u16)((u + 0x7FFFu + ((u >> 16) & 1u)) >> 16);
}

__device__ __forceinline__ float dot_bf(const u16* a, const u16* b, int K) {
    float acc = 0.0f;
    for (int k = 0; k < K; k += 8) {
        s8v av = *(const s8v*)(a + k);
        s8v bv = *(const s8v*)(b + k);
        #pragma unroll
        for (int j = 0; j < 8; ++j)
            acc += b2f((u16)av[j]) * b2f((u16)bv[j]);
    }
    return acc;
}
__device__ __forceinline__ float dot_f32(const float* a, const float* b, int K) {
    float acc = 0.0f;
    for (int k = 0; k < K; k += 8) {
        f4v a0 = *(const f4v*)(a + k);
        f4v a1 = *(const f4v*)(a + k + 4);
        f4v b0 = *(const f4v*)(b + k);
        f4v b1 = *(const f4v*)(b + k + 4);
        #pragma unroll
        for (int j = 0; j < 4; ++j) acc += a0[j]*b0[j];
        #pragma unroll
        for (int j = 0; j < 4; ++j) acc += a1[j]*b1[j];
    }
    return acc;
}
__device__ __forceinline__ bool step_active(const int* nsp, int t) {
    int ns = *nsp;                       // hedge: only trust sane values
    return !(ns >= 1 && ns <= T_ && t >= ns);
}
__device__ __forceinline__ int ns_eff(const int* nsp) {
    int ns = *nsp;
    return (ns >= 1 && ns <= T_) ? ns : T_;
}

__global__ __launch_bounds__(256) void k_zero(float* p, int n) {
    int i = blockIdx.x * 256 + threadIdx.x;
    if (i < n) p[i] = 0.0f;
}

// x is binary 0/1. fp32 words are only {0, 0x3F800000}; bf16-pair words hit
// low16 == 0x3F80 (element at even index == 1.0) with P~0.2/word.
// Also zeros the two persistent-GEMM tile counters.
__global__ void k_detect(const unsigned* __restrict__ xw, int* __restrict__ flag,
                         int* __restrict__ ctr) {
    unsigned v = xw[threadIdx.x];        // 64 words = 128 bf16 or 64 fp32
    unsigned long long m = __ballot((v & 0xFFFFu) == 0x3F80u);
    if (threadIdx.x == 0) *flag = (m != 0ull) ? 1 : 0;
    if (threadIdx.x < 2) ctr[threadIdx.x] = 0;
}

// ============================ FAST PATH ============================
// C[m,n] = sum_k A[m,k] * W[n,k];  A row-major [M_,K], W row-major [N=H_,K].
// bf16 variant: 2D grid (H_/128, M_/128), 4 waves, 64x64/wave via MFMA.
__global__ __launch_bounds__(256) void k_gemm_bf(
    const void* __restrict__ Av, const void* __restrict__ Wv,
    float* __restrict__ C, int K, const int* __restrict__ flag)
{
    if (!*flag) return;
    const u16* A = (const u16*)Av;
    const u16* W = (const u16*)Wv;
    const int wid  = threadIdx.x >> 6;
    const int lane = threadIdx.x & 63;
    const int mb = blockIdx.y * 128 + (wid >> 1) * 64;
    const int nb = blockIdx.x * 128 + (wid & 1) * 64;
    const int l15 = lane & 15, l4 = lane >> 4;

    const u16* ap[4]; const u16* bp[4];
    #pragma unroll
    for (int i = 0; i < 4; ++i) {
        ap[i] = A + (size_t)(mb + i*16 + l15) * K + l4*8;
        bp[i] = W + (size_t)(nb + i*16 + l15) * K + l4*8;
    }
    f32x4 acc[4][4] = {};
    for (int k0 = 0; k0 < K; k0 += 32) {
        s8v a[4], b[4];
        #pragma unroll
        for (int i = 0; i < 4; ++i) a[i] = *(const s8v*)(ap[i] + k0);
        #pragma unroll
        for (int i = 0; i < 4; ++i) b[i] = *(const s8v*)(bp[i] + k0);
        #pragma unroll
        for (int i = 0; i < 4; ++i)
            #pragma unroll
            for (int j = 0; j < 4; ++j)
                acc[i][j] = __builtin_amdgcn_mfma_f32_16x16x32_bf16(
                    a[i], b[j], acc[i][j], 0, 0, 0);
    }
    const int r0 = l4 * 4;
    #pragma unroll
    for (int i = 0; i < 4; ++i)
        #pragma unroll
        for (int j = 0; j < 4; ++j)
            #pragma unroll
            for (int r = 0; r < 4; ++r)
                C[(size_t)(mb + i*16 + r0 + r) * H_ + (nb + j*16 + l15)] =
                    acc[i][j][r];
}

// fp32 GEMM + FUSED membrane scan — PERSISTENT-BLOCK work queue.
// Round-12 lesson: wave-private/barrier-free LDS (64KB) halved occupancy
// (27->11.7%) and REGRESSED (441->508us); main loop reverted to the proven
// round-10 pipeline (VGPR 84, 32KB, barrier per K-tile, BANK_CONFLICT=0).
// Round-10/11 counters (VALUBusy 75%, Occ 27%) fit a RESIDENCY TAIL:
// 1024 equal blocks over 768 resident slots -> last 256 run at 1 block/CU
// for a full tile-time (makespan 2.0 vs 1.33 ideal). Fix: 768 persistent
// blocks grab tiles from an atomic queue (work-conserving, tail ~= 0).
// Tile pipeline, staging swizzle ((row>>1)&3, global-source side), k-order
// (g asc, e asc per output) all UNCHANGED -> absmax must stay 0.0.
// amode=0: A row-major [M][K]; amode=1: A = spk0 (t-major in out), logical
// row m=b*64+t -> addr (t*B_+b)*H_, t clamped to ns-1 (never consumed).
// __launch_bounds__(256,3) LOAD-BEARING (round 6: (256,4) spilled acc).
__global__ __launch_bounds__(256, 3) void k_gemm_f32_fused(
    const void* __restrict__ Av, int amode, const void* __restrict__ Wv,
    int K, void* __restrict__ outp, const void* __restrict__ thrp,
    size_t spk_off, size_t mem_off,
    const int* __restrict__ flag, const int* __restrict__ nsp,
    int* __restrict__ ctr)
{
    if (*flag) return;
    const float* A = (const float*)Av;
    const float* W = (const float*)Wv;
    __shared__ float ls[8192];   // arena: [0..4095]=A dbuf, [4096..8191]=W dbuf
    __shared__ int s_tile;       // queue broadcast (outside the arena)

    const int tid  = threadIdx.x;
    const int wid  = tid >> 6;
    const int lane = tid & 63;
    const int ns = ns_eff(nsp);
    const float thr = ((const float*)thrp)[0];
    float* po = (float*)outp;

    // ---- tile-independent decode ----
    const int seg0 = wid*2, seg1 = wid*2 + 1;
    const int srow0 = seg0*16 + (lane >> 2);
    const int srow1 = seg1*16 + (lane >> 2);
    const int ssl0 = (lane & 3) ^ ((srow0 >> 1) & 3);
    const int ssl1 = (lane & 3) ^ ((srow1 >> 1) & 3);
    const int m0 = (wid >> 1) * 64 + (lane >> 3);
    const int n0 = (wid & 1) * 64 + (lane & 7);
    const int sA = (m0 >> 1) & 3, sB = (n0 >> 1) & 3;
    const int sw = (m0 & 3) << 3;    // epilogue swizzle: col ^ ((row&3)<<3)
    const int nt = K >> 4;           // K/16

#define STAGE_TILE(KO, BUF) do {                                            \
    __builtin_amdgcn_global_load_lds((glb_f*)(gA0 + (KO)),                  \
        (lds_f*)&ls[(BUF)*2048 + seg0*256], 16, 0, 0);                      \
    __builtin_amdgcn_global_load_lds((glb_f*)(gA1 + (KO)),                  \
        (lds_f*)&ls[(BUF)*2048 + seg1*256], 16, 0, 0);                      \
    __builtin_amdgcn_global_load_lds((glb_f*)(gW0 + (KO)),                  \
        (lds_f*)&ls[4096 + (BUF)*2048 + seg0*256], 16, 0, 0);               \
    __builtin_amdgcn_global_load_lds((glb_f*)(gW1 + (KO)),                  \
        (lds_f*)&ls[4096 + (BUF)*2048 + seg1*256], 16, 0, 0);               \
} while (0)

    for (;;) {
        if (tid == 0) s_tile = atomicAdd(ctr, 1);
        __syncthreads();
        const int L = s_tile;            // uniform across block
        if (L >= NTILES) return;

        // XCD-style swizzle: L -> logical l; l = m_blk*8 + n_blk
        const int l  = ((L & 7) << 7) + (L >> 3);
        const int mb = (l >> 3) * 128;
        const int nb = (l & 7) * 128;

        // ---- per-tile staging pointers ----
        const float* gA0; const float* gA1;
        if (amode) {
            const int mg0 = mb + srow0, mg1 = mb + srow1;
            int tt0 = mg0 & 63; if (tt0 >= ns) tt0 = ns - 1;
            int tt1 = mg1 & 63; if (tt1 >= ns) tt1 = ns - 1;
            gA0 = A + (size_t)(tt0*B_ + (mg0 >> 6)) * H_ + ssl0*4;
            gA1 = A + (size_t)(tt1*B_ + (mg1 >> 6)) * H_ + ssl1*4;
        } else {
            gA0 = A + (size_t)(mb + srow0) * K + ssl0*4;
            gA1 = A + (size_t)(mb + srow1) * K + ssl1*4;
        }
        const float* gW0 = W + (size_t)(nb + srow0) * K + ssl0*4;
        const float* gW1 = W + (size_t)(nb + srow1) * K + ssl1*4;

        float acc[8][8] = {};

        STAGE_TILE(0, 0);
        __syncthreads();                 // drains the DMA (vmcnt(0))

        for (int t = 0; t < nt; ++t) {
            const int cur = t & 1;
            if (t + 1 < nt) STAGE_TILE((t + 1) << 4, cur ^ 1);
            const float* pa = &ls[cur*2048] + m0*16;
            const float* pw = &ls[4096 + cur*2048] + n0*16;
            #pragma unroll
            for (int g = 0; g < 4; ++g) {          // logical k-group, ascending
                const float* pag = pa + ((g ^ sA) << 2);
                const float* pwg = pw + ((g ^ sB) << 2);
                f4v a4[8], w4[8];
                #pragma unroll
                for (int i = 0; i < 8; ++i) a4[i] = *(const f4v*)(pag + i*128);
                #pragma unroll
                for (int j = 0; j < 8; ++j) w4[j] = *(const f4v*)(pwg + j*128);
                #pragma unroll
                for (int i = 0; i < 8; ++i)
                    #pragma unroll
                    for (int j = 0; j < 8; ++j)
                        #pragma unroll
                        for (int e = 0; e < 4; ++e)
                            acc[i][j] += a4[i][e] * w4[j][e];
            }
            __syncthreads();             // drains prefetch DMA + LDS reads
        }

        // ---- fused scan epilogue (arena reused; GEMM LDS data dead) ----
        #pragma unroll 1
        for (int p = 0; p < 2; ++p) {
            if ((wid >> 1) == p) {       // waves owning this b-half stage cur
                const int r0 = m0 & 63;
                #pragma unroll
                for (int i = 0; i < 8; ++i) {
                    float* row = ls + (r0 + 8*i) * 128;
                    #pragma unroll
                    for (int j = 0; j < 8; ++j)
                        row[(n0 + 8*j) ^ sw] = acc[i][j];
                }
            }
            __syncthreads();
            if (tid < 128) {             // 128 chains: thread = column h
                const int b = (mb >> 6) + p;
                const int h = nb + tid;
                float ms = 0.0f;
                for (int t = 0; t < ns; ++t) {
                    float cu = ls[t*128 + (tid ^ ((t & 3) << 3))];
                    float mnew = 0.5f*ms + cu - ((ms > thr) ? thr : 0.0f);
                    float sp = ((mnew - thr) > 0.0f) ? 1.0f : 0.0f;
                    ms = mnew;
                    size_t oi = (size_t)t*B_*H_ + (size_t)b*H_ + h;
                    po[spk_off + oi] = sp;
                    po[mem_off + oi] = ms;
                }
            }
            __syncthreads();             // also protects s_tile rewrite
        }
    }
#undef STAGE_TILE
}

// Elementwise membrane scan (bf16 path; f32 handled by the fused GEMM).
// xmajor=1: cur rows are m = b*T_ + t ; xmajor=0: m = t*B_ + b
__global__ __launch_bounds__(256) void k_scan(
    const float* __restrict__ cur, void* __restrict__ out,
    const void* __restrict__ thrp, size_t spk_off, size_t mem_off,
    int xmajor, const int* __restrict__ flag, const int* __restrict__ nsp,
    int bf_only)
{
    const int isbf = *flag;
    if (bf_only && !isbf) return;
    const int idx = blockIdx.x * 256 + threadIdx.x;   // 0 .. B_*H_-1
    const int h = idx & (H_ - 1);
    const int b = idx >> 10;
    const int ns = ns_eff(nsp);
    const float thr = isbf ? b2f(((const u16*)thrp)[0]) : ((const float*)thrp)[0];
    float m = 0.0f;
    for (int t = 0; t < ns; ++t) {
        size_t mi = xmajor ? ((size_t)b*T_ + t) : ((size_t)t*B_ + b);
        float c = cur[mi * H_ + h];
        float mnew = 0.5f*m + c - ((m > thr) ? thr : 0.0f);
        float sp = ((mnew - thr) > 0.0f) ? 1.0f : 0.0f;
        m = mnew;
        size_t oi = (size_t)t*B_*H_ + (size_t)b*H_ + h;
        if (isbf) {
            ((u16*)out)[spk_off + oi] = f2b(sp);
            ((u16*)out)[mem_off + oi] = f2b(m);
        } else {
            ((float*)out)[spk_off + oi] = sp;
            ((float*)out)[mem_off + oi] = m;
        }
    }
}

// Layer 2 matmul for ALL timesteps: cur2[m*2+o] = spk1[m,:] . W2[o,:]
__global__ __launch_bounds__(256) void k_l2all(
    const void* __restrict__ out, const void* __restrict__ W2,
    float* __restrict__ cur2, const int* __restrict__ flag)
{
    const int idx = blockIdx.x * 256 + threadIdx.x;   // 0 .. 2*M_-1
    const int m = idx >> 1, o = idx & 1;
    float c;
    if (*flag)
        c = dot_bf((const u16*)out + SPK1_OFF + (size_t)m*H_,
                   (const u16*)W2 + (size_t)o*H_, H_);
    else
        c = dot_f32((const float*)out + SPK1_OFF + (size_t)m*H_,
                    (const float*)W2 + (size_t)o*H_, H_);
    cur2[idx] = c;
}

__global__ __launch_bounds__(256) void k_scan2(
    const float* __restrict__ cur2, void* __restrict__ out,
    const void* __restrict__ thrp, const int* __restrict__ flag,
    const int* __restrict__ nsp)
{
    const int idx = blockIdx.x * 256 + threadIdx.x;
    if (idx >= B_*O_) return;
    const int b = idx >> 1, o = idx & 1;
    const int ns = ns_eff(nsp);
    const int isbf = *flag;
    const float thr = isbf ? b2f(((const u16*)thrp)[0]) : ((const float*)thrp)[0];
    float m = 0.0f;
    for (int t = 0; t < ns; ++t) {
        float c = cur2[(size_t)(t*B_ + b)*O_ + o];
        float mnew = 0.5f*m + c - ((m > thr) ? thr : 0.0f);
        float sp = ((mnew - thr) > 0.0f) ? 1.0f : 0.0f;
        m = mnew;
        size_t oi = (size_t)t*B_*O_ + (size_t)b*O_ + o;
        if (isbf) {
            ((u16*)out)[SPK2_OFF + oi] = f2b(sp);
            ((u16*)out)[MEM2_OFF + oi] = f2b(m);
        } else {
            ((float*)out)[SPK2_OFF + oi] = sp;
            ((float*)out)[MEM2_OFF + oi] = m;
        }
    }
}

// ====================== OLD (fallback) PATH ======================
__global__ __launch_bounds__(256) void k_l0(
    const void* __restrict__ x, const void* __restrict__ W0,
    const void* __restrict__ thrp, void* __restrict__ out,
    float* __restrict__ ms, const int* __restrict__ flag,
    const int* __restrict__ nsp, int t)
{
    if (!step_active(nsp, t)) return;
    const int isbf = *flag;
    const int b = blockIdx.y * 32 + (threadIdx.x & 31);
    const int h = blockIdx.x * 8 + (threadIdx.x >> 5);
    float thr, cur;
    if (isbf) {
        thr = b2f(((const u16*)thrp)[0]);
        cur = dot_bf((const u16*)x + (size_t)(b*T_ + t)*I_,
                     (const u16*)W0 + (size_t)h*I_, I_);
    } else {
        thr = ((const float*)thrp)[0];
        cur = dot_f32((const float*)x + (size_t)(b*T_ + t)*I_,
                      (const float*)W0 + (size_t)h*I_, I_);
    }
    float* msp = ms + b*H_ + h;
    float mp = *msp;
    float m = 0.5f*mp + cur - ((mp > thr) ? thr : 0.0f);
    float sp = ((m - thr) > 0.0f) ? 1.0f : 0.0f;
    *msp = m;
    size_t oi = (size_t)t*B_*H_ + (size_t)b*H_ + h;
    if (isbf) {
        ((u16*)out)[SPK0_OFF + oi] = f2b(sp);
        ((u16*)out)[MEM0_OFF + oi] = f2b(m);
    } else {
        ((float*)out)[SPK0_OFF + oi] = sp;
        ((float*)out)[MEM0_OFF + oi] = m;
    }
}

__global__ __launch_bounds__(256) void k_l1(
    const void* __restrict__ W1, const void* __restrict__ thrp,
    void* __restrict__ out, float* __restrict__ ms,
    const int* __restrict__ flag, const int* __restrict__ nsp, int t)
{
    if (!step_active(nsp, t)) return;
    const int isbf = *flag;
    const int b = blockIdx.y * 32 + (threadIdx.x & 31);
    const int h = blockIdx.x * 8 + (threadIdx.x >> 5);
    float thr, cur;
    size_t in_row = SPK0_OFF + (size_t)t*B_*H_ + (size_t)b*H_;
    if (isbf) {
        thr = b2f(((const u16*)thrp)[0]);
        cur = dot_bf((const u16*)out + in_row, (const u16*)W1 + (size_t)h*H_, H_);
    } else {
        thr = ((const float*)thrp)[0];
        cur = dot_f32((const float*)out + in_row, (const float*)W1 + (size_t)h*H_, H_);
    }
    float* msp = ms + b*H_ + h;
    float mp = *msp;
    float m = 0.5f*mp + cur - ((mp > thr) ? thr : 0.0f);
    float sp = ((m - thr) > 0.0f) ? 1.0f : 0.0f;
    *msp = m;
    size_t oi = (size_t)t*B_*H_ + (size_t)b*H_ + h;
    if (isbf) {
        ((u16*)out)[SPK1_OFF + oi] = f2b(sp);
        ((u16*)out)[MEM1_OFF + oi] = f2b(m);
    } else {
        ((float*)out)[SPK1_OFF + oi] = sp;
        ((float*)out)[MEM1_OFF + oi] = m;
    }
}

__global__ __launch_bounds__(256) void k_l2(
    const void* __restrict__ W2, const void* __restrict__ thrp,
    void* __restrict__ out, float* __restrict__ ms,
    const int* __restrict__ flag, const int* __restrict__ nsp, int t)
{
    if (!step_active(nsp, t)) return;
    const int isbf = *flag;
    const int b = blockIdx.x * 128 + (threadIdx.x >> 1);
    const int o = threadIdx.x & 1;
    float thr, cur;
    size_t in_row = SPK1_OFF + (size_t)t*B_*H_ + (size_t)b*H_;
    if (isbf) {
        thr = b2f(((const u16*)thrp)[0]);
        cur = dot_bf((const u16*)out + in_row, (const u16*)W2 + (size_t)o*H_, H_);
    } else {
        thr = ((const float*)thrp)[0];
        cur = dot_f32((const float*)out + in_row, (const float*)W2 + (size_t)o*H_, H_);
    }
    float* msp = ms + b*O_ + o;
    float mp = *msp;
    float m = 0.5f*mp + cur - ((mp > thr) ? thr : 0.0f);
    float sp = ((m - thr) > 0.0f) ? 1.0f : 0.0f;
    *msp = m;
    size_t oi = (size_t)t*B_*O_ + (size_t)b*O_ + o;
    if (isbf) {
        ((u16*)out)[SPK2_OFF + oi] = f2b(sp);
        ((u16*)out)[MEM2_OFF + oi] = f2b(m);
    } else {
        ((float*)out)[SPK2_OFF + oi] = sp;
        ((float*)out)[MEM2_OFF + oi] = m;
    }
}

extern "C" void kernel_launch(void* const* d_in, const int* in_sizes, int n_in,
                              void* d_out, int out_size, void* d_ws, size_t ws_size,
                              hipStream_t stream) {
    const void* x  = d_in[0];
    const void* W0 = d_in[1];
    const void* W1 = d_in[2];
    const void* W2 = d_in[3];
    const void* t0 = d_in[4];
    const void* t1 = d_in[5];
    const void* t2 = d_in[6];
    const int*  ns = (const int*)d_in[7];

    float* wsf  = (float*)d_ws;
    int*   flag = (int*)d_ws;
    int*   ctrs = (int*)d_ws + WS_CTR;

    // host-side dtype routing: x is B*T*I elements; 4B/elem = f32, 2B = bf16.
    // Unknown size -> launch both sets (device flag still gates each kernel).
    const int xb = in_sizes[0];
    const bool is_f32 = (xb == (int)((size_t)B_*T_*I_*4));
    const bool is_bf  = (xb == (int)((size_t)B_*T_*I_*2));
    const bool run_f32 = !is_bf;   // f32 or unknown
    const bool run_bf  = !is_f32;  // bf16 or unknown

    if (ws_size >= WS_FAST_TOTAL * sizeof(float)) {
        // -------- fast path --------
        // f32: persistent fused GEMM+scan; bf16: GEMM->cur->k_scan.
        float* cur  = wsf + WS_CUR;    // [M_ x H_] fp32 (bf16 path only)
        float* cur2 = wsf + WS_CUR2;   // [M_ x O_] fp32

        hipLaunchKernelGGL(k_detect, dim3(1), dim3(64), 0, stream,
                           (const unsigned*)x, flag, ctrs);

        // layer 0
        if (run_bf) {
            hipLaunchKernelGGL(k_gemm_bf, dim3(H_/128, M_/128), dim3(256), 0,
                               stream, x, W0, cur, I_, flag);
        }
        if (run_f32) {
            hipLaunchKernelGGL(k_gemm_f32_fused, dim3(NPERS), dim3(256), 0,
                               stream,
                               x, 0, W0, I_, d_out, t0, SPK0_OFF, MEM0_OFF,
                               flag, ns, ctrs + 0);
        }
        if (run_bf) {
            hipLaunchKernelGGL(k_scan, dim3(B_*H_/256), dim3(256), 0, stream,
                               cur, d_out, t0, SPK0_OFF, MEM0_OFF, 1, flag, ns, 1);
        }

        // layer 1 (f32 fused reads spk0 from out via amode=1 row remap)
        if (run_bf) {
            hipLaunchKernelGGL(k_gemm_bf, dim3(H_/128, M_/128), dim3(256), 0,
                               stream, d_out, W1, cur, H_, flag);
        }
        if (run_f32) {
            hipLaunchKernelGGL(k_gemm_f32_fused, dim3(NPERS), dim3(256), 0,
                               stream,
                               d_out, 1, W1, H_, d_out, t1, SPK1_OFF, MEM1_OFF,
                               flag, ns, ctrs + 1);
        }
        if (run_bf) {
            hipLaunchKernelGGL(k_scan, dim3(B_*H_/256), dim3(256), 0, stream,
                               cur, d_out, t1, SPK1_OFF, MEM1_OFF, 0, flag, ns, 1);
        }

        // layer 2
        hipLaunchKernelGGL(k_l2all, dim3(2*M_/256), dim3(256), 0, stream,
                           d_out, W2, cur2, flag);
        hipLaunchKernelGGL(k_scan2, dim3(2), dim3(256), 0, stream,
                           cur2, d_out, t2, flag, ns);
        return;
    }

    // -------- fallback: proven per-timestep path --------
    float* mem0 = wsf + WS_MEM0;
    float* mem1 = wsf + WS_MEM1;
    float* mem2 = wsf + WS_MEM2;

    hipLaunchKernelGGL(k_zero, dim3((WS_TOTAL + 255) / 256), dim3(256), 0, stream,
                       wsf, WS_TOTAL);
    hipLaunchKernelGGL(k_detect, dim3(1), dim3(64), 0, stream,
                       (const unsigned*)x, flag, ctrs);

    for (int t = 0; t < T_; ++t) {
        hipLaunchKernelGGL(k_l0, dim3(H_/8, B_/32), dim3(256), 0, stream,
                           x, W0, t0, d_out, mem0, flag, ns, t);
        hipLaunchKernelGGL(k_l1, dim3(H_/8, B_/32), dim3(256), 0, stream,
                           W1, t1, d_out, mem1, flag, ns, t);
        hipLaunchKernelGGL(k_l2, dim3(2), dim3(256), 0, stream,
                           W2, t2, d_out, mem2, flag, ns, t);
    }
}

// Round 14
// 855.201 us; speedup vs baseline: 3.3444x; 3.3444x over previous
//
#include <hip/hip_runtime.h>

typedef unsigned short u16;
typedef short s8v __attribute__((ext_vector_type(8)));   // 8 x bf16 (as shorts)
typedef float f4v __attribute__((ext_vector_type(4)));
typedef float f32x4 __attribute__((ext_vector_type(4)));

#define B_ 256
#define T_ 64
#define I_ 512
#define H_ 1024
#define O_ 2
#define M_ (T_*B_)   // 16384 rows in the big GEMMs

#define SPK0_OFF ((size_t)0)
#define SPK1_OFF ((size_t)T_*B_*H_)                  // 16777216
#define SPK2_OFF ((size_t)2*T_*B_*H_)                // 33554432
#define MEM0_OFF ((size_t)2*T_*B_*H_ + (size_t)T_*B_*O_)
#define MEM1_OFF (MEM0_OFF + (size_t)T_*B_*H_)
#define MEM2_OFF (MEM1_OFF + (size_t)T_*B_*H_)

// ---- workspace layout (floats) ----
// fallback (old) path:
#define WS_MEM0 1024
#define WS_MEM1 (1024 + B_*H_)
#define WS_MEM2 (1024 + 2*B_*H_)
#define WS_TOTAL (1024 + 2*B_*H_ + B_*O_)
// fast path: [0]=flag, cur2 scratch, big cur scratch (bf16 path only)
#define WS_CUR2 1024
#define WS_CUR  (1024 + T_*B_*O_)
#define WS_FAST_TOTAL ((size_t)WS_CUR + (size_t)M_*H_)   // floats

typedef const __attribute__((address_space(1))) float glb_f;
typedef __attribute__((address_space(3))) float lds_f;

__device__ __forceinline__ float b2f(u16 u) {
    return __uint_as_float(((unsigned)u) << 16);
}
__device__ __forceinline__ u16 f2b(float f) {  // RNE
    unsigned u = __float_as_uint(f);
    return (u16)((u + 0x7FFFu + ((u >> 16) & 1u)) >> 16);
}

__device__ __forceinline__ float dot_bf(const u16* a, const u16* b, int K) {
    float acc = 0.0f;
    for (int k = 0; k < K; k += 8) {
        s8v av = *(const s8v*)(a + k);
        s8v bv = *(const s8v*)(b + k);
        #pragma unroll
        for (int j = 0; j < 8; ++j)
            acc += b2f((u16)av[j]) * b2f((u16)bv[j]);
    }
    return acc;
}
__device__ __forceinline__ float dot_f32(const float* a, const float* b, int K) {
    float acc = 0.0f;
    for (int k = 0; k < K; k += 8) {
        f4v a0 = *(const f4v*)(a + k);
        f4v a1 = *(const f4v*)(a + k + 4);
        f4v b0 = *(const f4v*)(b + k);
        f4v b1 = *(const f4v*)(b + k + 4);
        #pragma unroll
        for (int j = 0; j < 4; ++j) acc += a0[j]*b0[j];
        #pragma unroll
        for (int j = 0; j < 4; ++j) acc += a1[j]*b1[j];
    }
    return acc;
}
__device__ __forceinline__ bool step_active(const int* nsp, int t) {
    int ns = *nsp;                       // hedge: only trust sane values
    return !(ns >= 1 && ns <= T_ && t >= ns);
}
__device__ __forceinline__ int ns_eff(const int* nsp) {
    int ns = *nsp;
    return (ns >= 1 && ns <= T_) ? ns : T_;
}

__global__ __launch_bounds__(256) void k_zero(float* p, int n) {
    int i = blockIdx.x * 256 + threadIdx.x;
    if (i < n) p[i] = 0.0f;
}

// x is binary 0/1. fp32 words are only {0, 0x3F800000}; bf16-pair words hit
// low16 == 0x3F80 (element at even index == 1.0) with P~0.2/word.
__global__ void k_detect(const unsigned* __restrict__ xw, int* __restrict__ flag) {
    unsigned v = xw[threadIdx.x];        // 64 words = 128 bf16 or 64 fp32
    unsigned long long m = __ballot((v & 0xFFFFu) == 0x3F80u);
    if (threadIdx.x == 0) *flag = (m != 0ull) ? 1 : 0;
}

// ============================ FAST PATH ============================
// C[m,n] = sum_k A[m,k] * W[n,k];  A row-major [M_,K], W row-major [N=H_,K].
// bf16 variant: 2D grid (H_/128, M_/128), 4 waves, 64x64/wave via MFMA.
__global__ __launch_bounds__(256) void k_gemm_bf(
    const void* __restrict__ Av, const void* __restrict__ Wv,
    float* __restrict__ C, int K, const int* __restrict__ flag)
{
    if (!*flag) return;
    const u16* A = (const u16*)Av;
    const u16* W = (const u16*)Wv;
    const int wid  = threadIdx.x >> 6;
    const int lane = threadIdx.x & 63;
    const int mb = blockIdx.y * 128 + (wid >> 1) * 64;
    const int nb = blockIdx.x * 128 + (wid & 1) * 64;
    const int l15 = lane & 15, l4 = lane >> 4;

    const u16* ap[4]; const u16* bp[4];
    #pragma unroll
    for (int i = 0; i < 4; ++i) {
        ap[i] = A + (size_t)(mb + i*16 + l15) * K + l4*8;
        bp[i] = W + (size_t)(nb + i*16 + l15) * K + l4*8;
    }
    f32x4 acc[4][4] = {};
    for (int k0 = 0; k0 < K; k0 += 32) {
        s8v a[4], b[4];
        #pragma unroll
        for (int i = 0; i < 4; ++i) a[i] = *(const s8v*)(ap[i] + k0);
        #pragma unroll
        for (int i = 0; i < 4; ++i) b[i] = *(const s8v*)(bp[i] + k0);
        #pragma unroll
        for (int i = 0; i < 4; ++i)
            #pragma unroll
            for (int j = 0; j < 4; ++j)
                acc[i][j] = __builtin_amdgcn_mfma_f32_16x16x32_bf16(
                    a[i], b[j], acc[i][j], 0, 0, 0);
    }
    const int r0 = l4 * 4;
    #pragma unroll
    for (int i = 0; i < 4; ++i)
        #pragma unroll
        for (int j = 0; j < 4; ++j)
            #pragma unroll
            for (int r = 0; r < 4; ++r)
                C[(size_t)(mb + i*16 + r0 + r) * H_ + (nb + j*16 + l15)] =
                    acc[i][j][r];
}

// fp32 GEMM + FUSED membrane scan. Rows are B-MAJOR: m = b*T_ + t.
// This is the EXACT round-10 proven configuration (861us total, L1=430us):
// static 1024-block grid, 32KB LDS double-buffer, global_load_lds DMA with
// the conflict-free (row>>1)&3 source swizzle (BANK_CONFLICT=0, round 6),
// simple inner loop (VGPR 84), barrier per K-tile, fused scan epilogue.
// Reverted here after rounds 11-13 proved the alternatives worse:
//  - quadrant operand blocking: NULL (compiler rescheduled, VGPR stuck 84)
//  - wave-private barrier-free 64KB LDS: -15% (occupancy 27->11.7%)
//  - persistent atomic tile queue: -230% (unsafe under graph/rocprof replay)
// amode=0: A row-major [M][K]; amode=1: A = spk0 (t-major in out), logical
// row m=b*64+t -> addr (t*B_+b)*H_, t clamped to ns-1 (never consumed).
// Per-output accumulation STRICTLY ascending-k -> absmax must stay 0.0.
// __launch_bounds__(256,3) LOAD-BEARING (round 6: (256,4) spilled acc).
__global__ __launch_bounds__(256, 3) void k_gemm_f32_fused(
    const void* __restrict__ Av, int amode, const void* __restrict__ Wv,
    int K, void* __restrict__ outp, const void* __restrict__ thrp,
    size_t spk_off, size_t mem_off,
    const int* __restrict__ flag, const int* __restrict__ nsp)
{
    if (*flag) return;
    const float* A = (const float*)Av;
    const float* W = (const float*)Wv;
    __shared__ float ls[8192];   // arena: [0..4095]=A dbuf, [4096..8191]=W dbuf

    const int tid  = threadIdx.x;
    const int wid  = tid >> 6;
    const int lane = tid & 63;
    // XCD swizzle: dispatch L -> logical l; l = m_blk*8 + n_blk
    const int L  = blockIdx.x;                 // 0..1023
    const int l  = ((L & 7) << 7) + (L >> 3);
    const int mb = (l >> 3) * 128;
    const int nb = (l & 7) * 128;

    const int ns = ns_eff(nsp);

    // ---- staging decode (constant per thread) ----
    const int seg0 = wid*2, seg1 = wid*2 + 1;
    const int srow0 = seg0*16 + (lane >> 2);
    const int srow1 = seg1*16 + (lane >> 2);
    const int ssl0 = (lane & 3) ^ ((srow0 >> 1) & 3);
    const int ssl1 = (lane & 3) ^ ((srow1 >> 1) & 3);
    const float* gA0; const float* gA1;
    if (amode) {
        const int mg0 = mb + srow0, mg1 = mb + srow1;
        int tt0 = mg0 & 63; if (tt0 >= ns) tt0 = ns - 1;
        int tt1 = mg1 & 63; if (tt1 >= ns) tt1 = ns - 1;
        gA0 = A + (size_t)(tt0*B_ + (mg0 >> 6)) * H_ + ssl0*4;
        gA1 = A + (size_t)(tt1*B_ + (mg1 >> 6)) * H_ + ssl1*4;
    } else {
        gA0 = A + (size_t)(mb + srow0) * K + ssl0*4;
        gA1 = A + (size_t)(mb + srow1) * K + ssl1*4;
    }
    const float* gW0 = W + (size_t)(nb + srow0) * K + ssl0*4;
    const float* gW1 = W + (size_t)(nb + srow1) * K + ssl1*4;

    // ---- compute mapping (identical to proven kernel) ----
    const int m0 = (wid >> 1) * 64 + (lane >> 3);
    const int n0 = (wid & 1) * 64 + (lane & 7);
    const int sA = (m0 >> 1) & 3, sB = (n0 >> 1) & 3;

    float acc[8][8] = {};

#define STAGE_TILE(KO, BUF) do {                                            \
    __builtin_amdgcn_global_load_lds((glb_f*)(gA0 + (KO)),                  \
        (lds_f*)&ls[(BUF)*2048 + seg0*256], 16, 0, 0);                      \
    __builtin_amdgcn_global_load_lds((glb_f*)(gA1 + (KO)),                  \
        (lds_f*)&ls[(BUF)*2048 + seg1*256], 16, 0, 0);                      \
    __builtin_amdgcn_global_load_lds((glb_f*)(gW0 + (KO)),                  \
        (lds_f*)&ls[4096 + (BUF)*2048 + seg0*256], 16, 0, 0);               \
    __builtin_amdgcn_global_load_lds((glb_f*)(gW1 + (KO)),                  \
        (lds_f*)&ls[4096 + (BUF)*2048 + seg1*256], 16, 0, 0);               \
} while (0)

    STAGE_TILE(0, 0);
    __syncthreads();                 // implicit vmcnt(0) drains the DMA

    const int nt = K >> 4;           // K/16
    for (int t = 0; t < nt; ++t) {
        const int cur = t & 1;
        if (t + 1 < nt) STAGE_TILE((t + 1) << 4, cur ^ 1);
        const float* pa = &ls[cur*2048] + m0*16;
        const float* pw = &ls[4096 + cur*2048] + n0*16;
        #pragma unroll
        for (int g = 0; g < 4; ++g) {          // logical k-group, ascending
            const float* pag = pa + ((g ^ sA) << 2);
            const float* pwg = pw + ((g ^ sB) << 2);
            f4v a4[8], w4[8];
            #pragma unroll
            for (int i = 0; i < 8; ++i) a4[i] = *(const f4v*)(pag + i*128);
            #pragma unroll
            for (int j = 0; j < 8; ++j) w4[j] = *(const f4v*)(pwg + j*128);
            #pragma unroll
            for (int i = 0; i < 8; ++i)
                #pragma unroll
                for (int j = 0; j < 8; ++j)
                    #pragma unroll
                    for (int e = 0; e < 4; ++e)
                        acc[i][j] += a4[i][e] * w4[j][e];
        }
        __syncthreads();             // drains prefetch DMA + LDS reads
    }
#undef STAGE_TILE

    // ---- fused scan epilogue (arena reused; all GEMM LDS data dead) ----
    const float thr = ((const float*)thrp)[0];
    float* po = (float*)outp;
    const int sw = (m0 & 3) << 3;    // write swizzle: col ^ ((row&3)<<3)
    #pragma unroll 1
    for (int p = 0; p < 2; ++p) {
        if ((wid >> 1) == p) {       // waves owning this b-half stage cur
            const int r0 = m0 & 63;
            #pragma unroll
            for (int i = 0; i < 8; ++i) {
                float* row = ls + (r0 + 8*i) * 128;
                #pragma unroll
                for (int j = 0; j < 8; ++j)
                    row[(n0 + 8*j) ^ sw] = acc[i][j];
            }
        }
        __syncthreads();
        if (tid < 128) {             // 128 chains: thread = column h
            const int b = (mb >> 6) + p;
            const int h = nb + tid;
            float ms = 0.0f;
            for (int t = 0; t < ns; ++t) {
                float cu = ls[t*128 + (tid ^ ((t & 3) << 3))];
                float mnew = 0.5f*ms + cu - ((ms > thr) ? thr : 0.0f);
                float sp = ((mnew - thr) > 0.0f) ? 1.0f : 0.0f;
                ms = mnew;
                size_t oi = (size_t)t*B_*H_ + (size_t)b*H_ + h;
                po[spk_off + oi] = sp;
                po[mem_off + oi] = ms;
            }
        }
        __syncthreads();
    }
}

// Elementwise membrane scan (bf16 path; f32 handled by the fused GEMM).
// xmajor=1: cur rows are m = b*T_ + t ; xmajor=0: m = t*B_ + b
__global__ __launch_bounds__(256) void k_scan(
    const float* __restrict__ cur, void* __restrict__ out,
    const void* __restrict__ thrp, size_t spk_off, size_t mem_off,
    int xmajor, const int* __restrict__ flag, const int* __restrict__ nsp,
    int bf_only)
{
    const int isbf = *flag;
    if (bf_only && !isbf) return;
    const int idx = blockIdx.x * 256 + threadIdx.x;   // 0 .. B_*H_-1
    const int h = idx & (H_ - 1);
    const int b = idx >> 10;
    const int ns = ns_eff(nsp);
    const float thr = isbf ? b2f(((const u16*)thrp)[0]) : ((const float*)thrp)[0];
    float m = 0.0f;
    for (int t = 0; t < ns; ++t) {
        size_t mi = xmajor ? ((size_t)b*T_ + t) : ((size_t)t*B_ + b);
        float c = cur[mi * H_ + h];
        float mnew = 0.5f*m + c - ((m > thr) ? thr : 0.0f);
        float sp = ((mnew - thr) > 0.0f) ? 1.0f : 0.0f;
        m = mnew;
        size_t oi = (size_t)t*B_*H_ + (size_t)b*H_ + h;
        if (isbf) {
            ((u16*)out)[spk_off + oi] = f2b(sp);
            ((u16*)out)[mem_off + oi] = f2b(m);
        } else {
            ((float*)out)[spk_off + oi] = sp;
            ((float*)out)[mem_off + oi] = m;
        }
    }
}

// Layer 2 matmul for ALL timesteps: cur2[m*2+o] = spk1[m,:] . W2[o,:]
__global__ __launch_bounds__(256) void k_l2all(
    const void* __restrict__ out, const void* __restrict__ W2,
    float* __restrict__ cur2, const int* __restrict__ flag)
{
    const int idx = blockIdx.x * 256 + threadIdx.x;   // 0 .. 2*M_-1
    const int m = idx >> 1, o = idx & 1;
    float c;
    if (*flag)
        c = dot_bf((const u16*)out + SPK1_OFF + (size_t)m*H_,
                   (const u16*)W2 + (size_t)o*H_, H_);
    else
        c = dot_f32((const float*)out + SPK1_OFF + (size_t)m*H_,
                    (const float*)W2 + (size_t)o*H_, H_);
    cur2[idx] = c;
}

__global__ __launch_bounds__(256) void k_scan2(
    const float* __restrict__ cur2, void* __restrict__ out,
    const void* __restrict__ thrp, const int* __restrict__ flag,
    const int* __restrict__ nsp)
{
    const int idx = blockIdx.x * 256 + threadIdx.x;
    if (idx >= B_*O_) return;
    const int b = idx >> 1, o = idx & 1;
    const int ns = ns_eff(nsp);
    const int isbf = *flag;
    const float thr = isbf ? b2f(((const u16*)thrp)[0]) : ((const float*)thrp)[0];
    float m = 0.0f;
    for (int t = 0; t < ns; ++t) {
        float c = cur2[(size_t)(t*B_ + b)*O_ + o];
        float mnew = 0.5f*m + c - ((m > thr) ? thr : 0.0f);
        float sp = ((mnew - thr) > 0.0f) ? 1.0f : 0.0f;
        m = mnew;
        size_t oi = (size_t)t*B_*O_ + (size_t)b*O_ + o;
        if (isbf) {
            ((u16*)out)[SPK2_OFF + oi] = f2b(sp);
            ((u16*)out)[MEM2_OFF + oi] = f2b(m);
        } else {
            ((float*)out)[SPK2_OFF + oi] = sp;
            ((float*)out)[MEM2_OFF + oi] = m;
        }
    }
}

// ====================== OLD (fallback) PATH ======================
__global__ __launch_bounds__(256) void k_l0(
    const void* __restrict__ x, const void* __restrict__ W0,
    const void* __restrict__ thrp, void* __restrict__ out,
    float* __restrict__ ms, const int* __restrict__ flag,
    const int* __restrict__ nsp, int t)
{
    if (!step_active(nsp, t)) return;
    const int isbf = *flag;
    const int b = blockIdx.y * 32 + (threadIdx.x & 31);
    const int h = blockIdx.x * 8 + (threadIdx.x >> 5);
    float thr, cur;
    if (isbf) {
        thr = b2f(((const u16*)thrp)[0]);
        cur = dot_bf((const u16*)x + (size_t)(b*T_ + t)*I_,
                     (const u16*)W0 + (size_t)h*I_, I_);
    } else {
        thr = ((const float*)thrp)[0];
        cur = dot_f32((const float*)x + (size_t)(b*T_ + t)*I_,
                      (const float*)W0 + (size_t)h*I_, I_);
    }
    float* msp = ms + b*H_ + h;
    float mp = *msp;
    float m = 0.5f*mp + cur - ((mp > thr) ? thr : 0.0f);
    float sp = ((m - thr) > 0.0f) ? 1.0f : 0.0f;
    *msp = m;
    size_t oi = (size_t)t*B_*H_ + (size_t)b*H_ + h;
    if (isbf) {
        ((u16*)out)[SPK0_OFF + oi] = f2b(sp);
        ((u16*)out)[MEM0_OFF + oi] = f2b(m);
    } else {
        ((float*)out)[SPK0_OFF + oi] = sp;
        ((float*)out)[MEM0_OFF + oi] = m;
    }
}

__global__ __launch_bounds__(256) void k_l1(
    const void* __restrict__ W1, const void* __restrict__ thrp,
    void* __restrict__ out, float* __restrict__ ms,
    const int* __restrict__ flag, const int* __restrict__ nsp, int t)
{
    if (!step_active(nsp, t)) return;
    const int isbf = *flag;
    const int b = blockIdx.y * 32 + (threadIdx.x & 31);
    const int h = blockIdx.x * 8 + (threadIdx.x >> 5);
    float thr, cur;
    size_t in_row = SPK0_OFF + (size_t)t*B_*H_ + (size_t)b*H_;
    if (isbf) {
        thr = b2f(((const u16*)thrp)[0]);
        cur = dot_bf((const u16*)out + in_row, (const u16*)W1 + (size_t)h*H_, H_);
    } else {
        thr = ((const float*)thrp)[0];
        cur = dot_f32((const float*)out + in_row, (const float*)W1 + (size_t)h*H_, H_);
    }
    float* msp = ms + b*H_ + h;
    float mp = *msp;
    float m = 0.5f*mp + cur - ((mp > thr) ? thr : 0.0f);
    float sp = ((m - thr) > 0.0f) ? 1.0f : 0.0f;
    *msp = m;
    size_t oi = (size_t)t*B_*H_ + (size_t)b*H_ + h;
    if (isbf) {
        ((u16*)out)[SPK1_OFF + oi] = f2b(sp);
        ((u16*)out)[MEM1_OFF + oi] = f2b(m);
    } else {
        ((float*)out)[SPK1_OFF + oi] = sp;
        ((float*)out)[MEM1_OFF + oi] = m;
    }
}

__global__ __launch_bounds__(256) void k_l2(
    const void* __restrict__ W2, const void* __restrict__ thrp,
    void* __restrict__ out, float* __restrict__ ms,
    const int* __restrict__ flag, const int* __restrict__ nsp, int t)
{
    if (!step_active(nsp, t)) return;
    const int isbf = *flag;
    const int b = blockIdx.x * 128 + (threadIdx.x >> 1);
    const int o = threadIdx.x & 1;
    float thr, cur;
    size_t in_row = SPK1_OFF + (size_t)t*B_*H_ + (size_t)b*H_;
    if (isbf) {
        thr = b2f(((const u16*)thrp)[0]);
        cur = dot_bf((const u16*)out + in_row, (const u16*)W2 + (size_t)o*H_, H_);
    } else {
        thr = ((const float*)thrp)[0];
        cur = dot_f32((const float*)out + in_row, (const float*)W2 + (size_t)o*H_, H_);
    }
    float* msp = ms + b*O_ + o;
    float mp = *msp;
    float m = 0.5f*mp + cur - ((mp > thr) ? thr : 0.0f);
    float sp = ((m - thr) > 0.0f) ? 1.0f : 0.0f;
    *msp = m;
    size_t oi = (size_t)t*B_*O_ + (size_t)b*O_ + o;
    if (isbf) {
        ((u16*)out)[SPK2_OFF + oi] = f2b(sp);
        ((u16*)out)[MEM2_OFF + oi] = f2b(m);
    } else {
        ((float*)out)[SPK2_OFF + oi] = sp;
        ((float*)out)[MEM2_OFF + oi] = m;
    }
}

extern "C" void kernel_launch(void* const* d_in, const int* in_sizes, int n_in,
                              void* d_out, int out_size, void* d_ws, size_t ws_size,
                              hipStream_t stream) {
    const void* x  = d_in[0];
    const void* W0 = d_in[1];
    const void* W1 = d_in[2];
    const void* W2 = d_in[3];
    const void* t0 = d_in[4];
    const void* t1 = d_in[5];
    const void* t2 = d_in[6];
    const int*  ns = (const int*)d_in[7];

    float* wsf  = (float*)d_ws;
    int*   flag = (int*)d_ws;

    // host-side dtype routing: x is B*T*I elements; 4B/elem = f32, 2B = bf16.
    // Unknown size -> launch both sets (device flag still gates each kernel).
    const int xb = in_sizes[0];
    const bool is_f32 = (xb == (int)((size_t)B_*T_*I_*4));
    const bool is_bf  = (xb == (int)((size_t)B_*T_*I_*2));
    const bool run_f32 = !is_bf;   // f32 or unknown
    const bool run_bf  = !is_f32;  // bf16 or unknown

    if (ws_size >= WS_FAST_TOTAL * sizeof(float)) {
        // -------- fast path --------
        // f32: fused GEMM+scan (no cur round-trip); bf16: GEMM->cur->k_scan.
        float* cur  = wsf + WS_CUR;    // [M_ x H_] fp32 (bf16 path only)
        float* cur2 = wsf + WS_CUR2;   // [M_ x O_] fp32

        hipLaunchKernelGGL(k_detect, dim3(1), dim3(64), 0, stream,
                           (const unsigned*)x, flag);

        // layer 0
        if (run_bf) {
            hipLaunchKernelGGL(k_gemm_bf, dim3(H_/128, M_/128), dim3(256), 0,
                               stream, x, W0, cur, I_, flag);
        }
        if (run_f32) {
            hipLaunchKernelGGL(k_gemm_f32_fused, dim3((M_/128)*(H_/128)),
                               dim3(256), 0, stream,
                               x, 0, W0, I_, d_out, t0, SPK0_OFF, MEM0_OFF,
                               flag, ns);
        }
        if (run_bf) {
            hipLaunchKernelGGL(k_scan, dim3(B_*H_/256), dim3(256), 0, stream,
                               cur, d_out, t0, SPK0_OFF, MEM0_OFF, 1, flag, ns, 1);
        }

        // layer 1 (f32 fused reads spk0 from out via amode=1 row remap)
        if (run_bf) {
            hipLaunchKernelGGL(k_gemm_bf, dim3(H_/128, M_/128), dim3(256), 0,
                               stream, d_out, W1, cur, H_, flag);
        }
        if (run_f32) {
            hipLaunchKernelGGL(k_gemm_f32_fused, dim3((M_/128)*(H_/128)),
                               dim3(256), 0, stream,
                               d_out, 1, W1, H_, d_out, t1, SPK1_OFF, MEM1_OFF,
                               flag, ns);
        }
        if (run_bf) {
            hipLaunchKernelGGL(k_scan, dim3(B_*H_/256), dim3(256), 0, stream,
                               cur, d_out, t1, SPK1_OFF, MEM1_OFF, 0, flag, ns, 1);
        }

        // layer 2
        hipLaunchKernelGGL(k_l2all, dim3(2*M_/256), dim3(256), 0, stream,
                           d_out, W2, cur2, flag);
        hipLaunchKernelGGL(k_scan2, dim3(2), dim3(256), 0, stream,
                           cur2, d_out, t2, flag, ns);
        return;
    }

    // -------- fallback: proven per-timestep path --------
    float* mem0 = wsf + WS_MEM0;
    float* mem1 = wsf + WS_MEM1;
    float* mem2 = wsf + WS_MEM2;

    hipLaunchKernelGGL(k_zero, dim3((WS_TOTAL + 255) / 256), dim3(256), 0, stream,
                       wsf, WS_TOTAL);
    hipLaunchKernelGGL(k_detect, dim3(1), dim3(64), 0, stream,
                       (const unsigned*)x, flag);

    for (int t = 0; t < T_; ++t) {
        hipLaunchKernelGGL(k_l0, dim3(H_/8, B_/32), dim3(256), 0, stream,
                           x, W0, t0, d_out, mem0, flag, ns, t);
        hipLaunchKernelGGL(k_l1, dim3(H_/8, B_/32), dim3(256), 0, stream,
                           W1, t1, d_out, mem1, flag, ns, t);
        hipLaunchKernelGGL(k_l2, dim3(2), dim3(256), 0, stream,
                           W2, t2, d_out, mem2, flag, ns, t);
    }
}